// Round 24
// baseline (40.991 us; speedup 1.0000x reference)
//
#include <hip/hip_runtime.h>
#include <hip/hip_fp16.h>

// DifferentiableRankIntegration, B=1024, tau=0.1, K=60.
// R24 = R23 fully fused: ONE kernel, one block per row, both matrices run
// sequentially through the same LDS pool (combine kernel + 8MB rank_ws
// eliminated; masks/cat read once; pass-1 ranks held in registers while
// pass 2 reuses the pool). Per-matrix numerics bit-identical to R23:
// value-bucket compaction (NB=60, W>=1.0, cat in En mantissa LSBs), exact
// weighted quartic rational + 3-term geometric tails evaluated at the 60
// bucket-center nodes only, then 4-point Lagrange cubic interpolation.
constexpr int B = 1024;
constexpr int NT = 256;
constexpr int NB = 60;
constexpr int SLOTCAP = 1216;
constexpr int QCAP = SLOTCAP / 4;  // 304
constexpr int QPHYS = QCAP + (QCAP >> 4) + 1;  // 324
constexpr float L2E = 1.4426950408889634f;
constexpr int TCOLS = NB + 6;      // 66

constexpr int OFF_EN  = 0;                        // 4864 B
constexpr int OFF_CQ  = OFF_EN + SLOTCAP * 4;     // CeAll+ChAll = 10368 B
                                                  //  (post-4: ANnode/APnode)
constexpr int OFF_SEG = OFF_CQ + 2 * QPHYS * 16;  // segCnt 960 + segPre 1920
                                                  //  (phase>=3: Tab 14x66x4)
constexpr int OFF_SST = OFF_SEG + 14 * TCOLS * 4; // segStart 61*4 = 244 B
constexpr int OFF_RED = OFF_SST + (NB + 1) * 4;   // Red 64 B
constexpr int POOL_BYTES = ((OFF_RED + 64 + 15) / 16) * 16;  // ~19.6 KB

__global__ __launch_bounds__(NT, 8)
void rank_fused_kernel(const float* __restrict__ s_v, const float* __restrict__ s_l,
                       const int* __restrict__ pos_m, const int* __restrict__ neg_m,
                       const float* __restrict__ w_v, const float* __restrict__ w_l,
                       float* __restrict__ out) {
    __shared__ __align__(16) char pool[POOL_BYTES];
    float* En          = (float*)(pool + OFF_EN);
    float4* CeAll      = (float4*)(pool + OFF_CQ);
    uint4* ChAll       = (uint4*)(pool + OFF_CQ + QPHYS*16);
    unsigned char (*segCnt)[16]  = (unsigned char(*)[16])(pool + OFF_SEG);
    unsigned short (*segPre)[16] = (unsigned short(*)[16])(pool + OFF_SEG + NB*16);
    float* TabF        = (float*)(pool + OFF_SEG);
    int* segStart      = (int*)(pool + OFF_SST);
    float* Red         = (float*)(pool + OFF_RED);    // [2 matrices][min/max][4]
    float* ANnode      = (float*)(pool + OFF_CQ);     // post-phase-4 overlay
    float* APnode      = ANnode + 64;

    const int r = blockIdx.x;
    const int tid = threadIdx.x;
    const int lane = tid & 63;
    const int wvid = tid >> 6;
    const unsigned long long lmask = (1ull << lane) - 1ull;

    // ---- Phase 1 (shared): read both matrices + masks, cat, min/max both ----
    float uu[2][4]; int cat[4];
    float mn0 = 1e30f, mx0 = -1e30f, mn1 = 1e30f, mx1 = -1e30f;
#pragma unroll
    for (int i = 0; i < 4; ++i) {
        const int c = tid + i * NT;
        uu[0][i] = s_v[r * B + c] * 10.0f;
        uu[1][i] = s_l[r * B + c] * 10.0f;
        const int pf = pos_m[r * B + c] != 0, nf = neg_m[r * B + c] != 0;
        cat[i] = pf | (nf << 1);
        mn0 = fminf(mn0, uu[0][i]); mx0 = fmaxf(mx0, uu[0][i]);
        mn1 = fminf(mn1, uu[1][i]); mx1 = fmaxf(mx1, uu[1][i]);
    }
#pragma unroll
    for (int off = 1; off < 64; off <<= 1) {
        mn0 = fminf(mn0, __shfl_xor(mn0, off)); mx0 = fmaxf(mx0, __shfl_xor(mx0, off));
        mn1 = fminf(mn1, __shfl_xor(mn1, off)); mx1 = fmaxf(mx1, __shfl_xor(mx1, off));
    }
    if (lane == 0) {
        Red[0 + wvid] = mn0; Red[4 + wvid] = mx0;
        Red[8 + wvid] = mn1; Red[12 + wvid] = mx1;
    }
    __syncthreads();

    float umin2[2], Wb2[2], invW2[2], kapA[2], kapB[2], kapC[2], eWm2[2];
#pragma unroll
    for (int mp = 0; mp < 2; ++mp) {
        const float lo = fminf(fminf(Red[8*mp+0], Red[8*mp+1]), fminf(Red[8*mp+2], Red[8*mp+3]));
        const float hi = fmaxf(fmaxf(Red[8*mp+4], Red[8*mp+5]), fmaxf(Red[8*mp+6], Red[8*mp+7]));
        umin2[mp] = lo;
        Wb2[mp]   = fmaxf((hi - lo) * (1.0001f / NB), 1.0f);
        invW2[mp] = 1.0f / Wb2[mp];
        kapA[mp]  = exp2f(-Wb2[mp] * L2E);
        kapB[mp]  = kapA[mp] * kapA[mp];
        kapC[mp]  = kapB[mp] * kapA[mp];
        eWm2[mp]  = exp2f(Wb2[mp] * L2E);
    }

    float rkm[2][4];   // per-matrix interpolated ranks

#pragma unroll
    for (int mp = 0; mp < 2; ++mp) {
        const float umin = umin2[mp], Wb = Wb2[mp], invW = invW2[mp];
        const float kap1 = kapA[mp], kap2 = kapB[mp], kap3 = kapC[mp], eWm = eWm2[mp];

        // ---- zero En + segCnt for this pass ----
        __syncthreads();   // (pass 1: after interp reads; pass 0: after Red reads)
        for (int s = tid; s < SLOTCAP; s += NT) En[s] = 0.f;
        for (int j = tid; j < NB * 16 / 4; j += NT) ((int*)segCnt)[j] = 0;
        __syncthreads();

        // ---- 1b: bucket keys; rank via 6 bit-ballots ----
        int key[4], rk[4];
#pragma unroll
        for (int i = 0; i < 4; ++i) {
            int b = (int)((uu[mp][i] - umin) * invW);
            b = b > NB - 1 ? NB - 1 : b;
            const int kk = cat[i] ? b : 63;
            key[i] = b;
            unsigned long long same = ~0ull;
#pragma unroll
            for (int j = 0; j < 6; ++j) {
                const unsigned long long bb = __ballot((kk >> j) & 1);
                same &= ((kk >> j) & 1) ? bb : ~bb;
            }
            rk[i] = (int)__popcll(same & lmask);
            if (cat[i] && rk[i] == 0)
                segCnt[kk][i * 4 + wvid] = (unsigned char)__popcll(same);
        }
        __syncthreads();

        // ---- 2a: segPre + wave-0 prefix scan ----
        for (int j = tid; j < NB * 16; j += NT) {
            const int k = j >> 4, u = j & 15;
            int p = 0;
            for (int v = 0; v < u; ++v) p += (int)segCnt[k][v];
            segPre[k][u] = (unsigned short)p;
        }
        if (wvid == 0) {
            int t = 0;
            if (lane < NB) {
#pragma unroll
                for (int u = 0; u < 16; ++u) t += (int)segCnt[lane][u];
                t = (t + 3) & ~3;
            }
            int inc = t;
#pragma unroll
            for (int d = 1; d < 64; d <<= 1) {
                const int o = __shfl_up(inc, d);
                if (lane >= d) inc += o;
            }
            if (lane < NB) segStart[lane] = inc - t;
            if (lane == NB - 1) segStart[NB] = inc;
        }
        __syncthreads();

        // ---- 2b: scatter En (cat in mantissa LSBs) ----
#pragma unroll
        for (int i = 0; i < 4; ++i) {
            if (cat[i]) {
                const int k = key[i];
                const int slot = segStart[k] + (int)segPre[k][i * 4 + wvid] + rk[i];
                const float cb = umin + ((float)k + 0.5f) * Wb;
                const float env = exp2f((uu[mp][i] - cb) * L2E);
                unsigned eb = __float_as_uint(env);
                eb = (eb & ~3u) | (unsigned)cat[i];
                En[slot] = __uint_as_float(eb);
            }
        }
        __syncthreads();   // segCnt/segPre dead -> Tab overlay valid

        const int nS = segStart[NB];
        const int nQ = nS >> 2;

        // ---- 3a: Tab boundary zeros + quad coefficients ----
        if (tid < 14 * 6) {
            const int row = tid / 6, ci = tid % 6;
            TabF[row * TCOLS + (ci < 2 ? ci : ci + 60)] = 0.f;
        }
        for (int q = tid; q < nQ; q += NT) {
            const float4 e4v = *(const float4*)&En[4 * q];
            const float en[4] = {e4v.x, e4v.y, e4v.z, e4v.w};
            const int fl[4] = {(int)(__float_as_uint(e4v.x) & 3u),
                               (int)(__float_as_uint(e4v.y) & 3u),
                               (int)(__float_as_uint(e4v.z) & 3u),
                               (int)(__float_as_uint(e4v.w) & 3u)};
            const float s01 = en[0] + en[1], p01 = en[0] * en[1];
            const float s23 = en[2] + en[3], p23 = en[2] * en[3];
            const float e1 = s01 + s23;
            const float e2 = fmaf(s01, s23, p01 + p23);
            const float e3 = fmaf(s01, p23, s23 * p01);
            const float e4 = p01 * p23;
            float nA3 = 0.f, nA2 = 0.f, nA1 = 0.f, nA0 = 0.f;
            float nP3 = 0.f, nP2 = 0.f, nP1 = 0.f, nP0 = 0.f;
#pragma unroll
            for (int j = 0; j < 4; ++j) {
                const float b1 = e1 - en[j];
                const float b2 = fmaf(-en[j], b1, e2);
                const float b3 = fmaf(-en[j], b2, e3);
                const float nn = (float)(fl[j] >> 1) * en[j];
                const float pp = (float)(fl[j] & 1) * en[j];
                nA3 += nn; nA2 = fmaf(nn, b1, nA2); nA1 = fmaf(nn, b2, nA1); nA0 = fmaf(nn, b3, nA0);
                nP3 += pp; nP2 = fmaf(pp, b1, nP2); nP1 = fmaf(pp, b2, nP1); nP0 = fmaf(pp, b3, nP0);
            }
            const int pq = q + (q >> 4);
            CeAll[pq] = make_float4(e1, e2, e3, e4);
            __half2 hA0 = __floats2half2_rn(nA3, nA2);
            __half2 hA1 = __floats2half2_rn(nA1, nA0);
            __half2 hP0 = __floats2half2_rn(nP3, nP2);
            __half2 hP1 = __floats2half2_rn(nP1, nP0);
            ChAll[pq] = make_uint4(reinterpret_cast<unsigned&>(hA0), reinterpret_cast<unsigned&>(hA1),
                                   reinterpret_cast<unsigned&>(hP0), reinterpret_cast<unsigned&>(hP1));
        }
        // ---- 3b: per-bucket tail sums ----
        if (tid < NB * 4) {
            const int k = tid >> 2, o = tid & 3;
            float g1a=0,g2a=0,g3a=0,h1a=0,h2a=0,h3a=0,s0a=0;
            float g1p=0,g2p=0,g3p=0,h1p=0,h2p=0,h3p=0,s0p=0;
            for (int s = segStart[k] + o; s < segStart[k + 1]; s += 4) {
                const float en = En[s];
                const int f = (int)(__float_as_uint(en) & 3u);
                if (!f) continue;
                const float en2 = en * en, en3 = en2 * en;
                const float ren = __builtin_amdgcn_rcpf(en);
                const float ren2 = ren * ren, ren3 = ren2 * ren;
                const float nf = (float)(f >> 1), pf = (float)(f & 1);
                g1a = fmaf(nf,en,g1a);  g2a = fmaf(nf,en2,g2a);  g3a = fmaf(nf,en3,g3a);
                h1a = fmaf(nf,ren,h1a); h2a = fmaf(nf,ren2,h2a); h3a = fmaf(nf,ren3,h3a); s0a += nf;
                g1p = fmaf(pf,en,g1p);  g2p = fmaf(pf,en2,g2p);  g3p = fmaf(pf,en3,g3p);
                h1p = fmaf(pf,ren,h1p); h2p = fmaf(pf,ren2,h2p); h3p = fmaf(pf,ren3,h3p); s0p += pf;
            }
#define RED4(v) v += __shfl_xor(v, 2); v += __shfl_xor(v, 1)
            RED4(g1a); RED4(g2a); RED4(g3a); RED4(h1a); RED4(h2a); RED4(h3a); RED4(s0a);
            RED4(g1p); RED4(g2p); RED4(g3p); RED4(h1p); RED4(h2p); RED4(h3p); RED4(s0p);
#undef RED4
            if (o == 0) {
                TabF[(0*7+0)*TCOLS+k+2]=g1a; TabF[(0*7+1)*TCOLS+k+2]=g2a; TabF[(0*7+2)*TCOLS+k+2]=g3a;
                TabF[(0*7+3)*TCOLS+k+2]=h1a; TabF[(0*7+4)*TCOLS+k+2]=h2a; TabF[(0*7+5)*TCOLS+k+2]=h3a;
                TabF[(0*7+6)*TCOLS+k+2]=s0a;
                TabF[(1*7+0)*TCOLS+k+2]=g1p; TabF[(1*7+1)*TCOLS+k+2]=g2p; TabF[(1*7+2)*TCOLS+k+2]=g3p;
                TabF[(1*7+3)*TCOLS+k+2]=h1p; TabF[(1*7+4)*TCOLS+k+2]=h2p; TabF[(1*7+5)*TCOLS+k+2]=h3p;
                TabF[(1*7+6)*TCOLS+k+2]=s0p;
            }
        }
        __syncthreads();
        // ---- 3c: wave-parallel weighted scans ----
        for (int rowi = wvid; rowi < 14; rowi += 4) {
            const int r7 = rowi % 7;
            float* Trow = &TabF[rowi * TCOLS];
            float v = (lane < NB) ? Trow[lane + 2] : 0.f;
            if (r7 < 3) {
                float kp = (r7 == 0) ? kap1 : (r7 == 1 ? kap2 : kap3);
#pragma unroll
                for (int d = 1; d < 64; d <<= 1) {
                    const float o = __shfl_up(v, d);
                    if (lane >= d) v = fmaf(kp, o, v);
                    kp *= kp;
                }
            } else {
                float kp = (r7 == 3) ? kap1 : (r7 == 4 ? kap2 : (r7 == 5 ? kap3 : 1.0f));
#pragma unroll
                for (int d = 1; d < 64; d <<= 1) {
                    float o = __shfl_down(v, d);
                    if (lane + d > 63) o = 0.f;
                    v = fmaf(kp, o, v);
                    kp *= kp;
                }
            }
            if (lane < NB) Trow[lane + 2] = v;
        }
        __syncthreads();

        // ---- 4: node evaluation (4 threads per node) ----
        const int nd = tid >> 2;
        const int no = tid & 3;
        float ANv = 0.f, APv = 0.f;
        if (nd < NB) {
            const int klo = nd > 0 ? nd - 1 : 0;
            const int khi = nd < NB - 1 ? nd + 1 : NB - 1;
            const int qs  = segStart[klo] >> 2;
            const int qe  = segStart[khi + 1] >> 2;
            const int qo0 = segStart[nd] >> 2;
            const int qo1 = segStart[nd + 1] >> 2;
            for (int q = qs + no; q < qe; q += 4) {
                const float x = (q < qo0) ? eWm : ((q >= qo1) ? kap1 : 1.0f);
                const int pq = q + (q >> 4);
                const float4 ce = CeAll[pq];
                const uint4 ch = ChAll[pq];
                const float2 a01 = __half22float2(*(const __half2*)&ch.x);
                const float2 a23 = __half22float2(*(const __half2*)&ch.y);
                const float2 p01 = __half22float2(*(const __half2*)&ch.z);
                const float2 p23 = __half22float2(*(const __half2*)&ch.w);
                float t = x + ce.x; t = fmaf(t, x, ce.y); t = fmaf(t, x, ce.z);
                const float D = fmaf(t, x, ce.w);
                float u = fmaf(a01.x, x, a01.y); u = fmaf(u, x, a23.x);
                const float NA = fmaf(u, x, a23.y);
                float v = fmaf(p01.x, x, p01.y); v = fmaf(v, x, p23.x);
                const float NP = fmaf(v, x, p23.y);
                const float rd = __builtin_amdgcn_rcpf(D);
                ANv = fmaf(NA, rd, ANv);
                APv = fmaf(NP, rd, APv);
            }
            ANv += __shfl_xor(ANv, 2); ANv += __shfl_xor(ANv, 1);
            APv += __shfl_xor(APv, 2); APv += __shfl_xor(APv, 1);
            const float k2 = kap2, k4 = kap2 * kap2, k6 = k4 * kap2;
            ANv += k2 * TabF[(0*7+0)*TCOLS+nd] - k4 * TabF[(0*7+1)*TCOLS+nd] + k6 * TabF[(0*7+2)*TCOLS+nd]
                 + TabF[(0*7+6)*TCOLS+nd+4] - k2 * TabF[(0*7+3)*TCOLS+nd+4]
                 + k4 * TabF[(0*7+4)*TCOLS+nd+4] - k6 * TabF[(0*7+5)*TCOLS+nd+4];
            APv += k2 * TabF[(1*7+0)*TCOLS+nd] - k4 * TabF[(1*7+1)*TCOLS+nd] + k6 * TabF[(1*7+2)*TCOLS+nd]
                 + TabF[(1*7+6)*TCOLS+nd+4] - k2 * TabF[(1*7+3)*TCOLS+nd+4]
                 + k4 * TabF[(1*7+4)*TCOLS+nd+4] - k6 * TabF[(1*7+5)*TCOLS+nd+4];
        }
        __syncthreads();   // Cq reads done -> node overlay safe
        if (nd < NB && no == 0) { ANnode[nd] = ANv; APnode[nd] = APv; }
        __syncthreads();

        // ---- 5: per-item cubic interpolation into registers ----
#pragma unroll
        for (int i = 0; i < 4; ++i) {
            const float t = (uu[mp][i] - umin) * invW - 0.5f;
            int jc = (int)floorf(t);
            jc = jc < 1 ? 1 : (jc > NB - 3 ? NB - 3 : jc);
            const float s = t - (float)jc;
            const float sm = s - 1.f, sp = s + 1.f, s2 = s - 2.f;
            const float wL = -s * sm * s2 * (1.f / 6.f);
            const float w0 = sp * sm * s2 * 0.5f;
            const float w1 = -sp * s * s2 * 0.5f;
            const float w2 = sp * s * sm * (1.f / 6.f);
            const float AN = wL * ANnode[jc-1] + w0 * ANnode[jc] + w1 * ANnode[jc+1] + w2 * ANnode[jc+2];
            const float AP = wL * APnode[jc-1] + w0 * APnode[jc] + w1 * APnode[jc+1] + w2 * APnode[jc+2];
            const bool pf = (cat[i] & 1) != 0;
            const bool nf = (cat[i] & 2) != 0;
            rkm[mp][i] = (pf ? 1.f + AN : 0.f) + (nf ? 1.f + AP : 0.f);
        }
    }

    // ---- Epilogue: fused output ----
#pragma unroll
    for (int i = 0; i < 4; ++i) {
        const int c = tid + i * NT;
        const float wv = w_v[r * B + c];
        const float wl = w_l[r * B + c];
        out[r * B + c] = 61.f * (wv / (60.f + rkm[0][i]) + wl / (60.f + rkm[1][i]));
    }
}

extern "C" void kernel_launch(void* const* d_in, const int* in_sizes, int n_in,
                              void* d_out, int out_size, void* d_ws, size_t ws_size,
                              hipStream_t stream) {
    const float* s_v = (const float*)d_in[0];
    const float* s_l = (const float*)d_in[1];
    const int* pos_mask = (const int*)d_in[2];
    const int* neg_mask = (const int*)d_in[3];
    const float* w_v = (const float*)d_in[4];
    const float* w_l = (const float*)d_in[5];
    float* out = (float*)d_out;

    rank_fused_kernel<<<B, NT, 0, stream>>>(s_v, s_l, pos_mask, neg_mask,
                                            w_v, w_l, out);
}

// Round 25
// 33.222 us; speedup vs baseline: 1.2339x; 1.2339x over previous
//
#include <hip/hip_runtime.h>
#include <hip/hip_fp16.h>

// DifferentiableRankIntegration, B=1024, tau=0.1, K=60.
// R25 = R23 (best structure: 2048 blocks, one per (matrix,row)) with the
// combine kernel REPLACED by direct atomic accumulation: each block adds
// 61*w_m/(60+rank_m) into out (exactly 2 commutative fp32 adds per element,
// deterministic); out zeroed via hipMemsetAsync on-stream. R24 lesson:
// fusing both matrices into one block doubles the serial barrier chain and
// halves grid parallelism -> regression; keep the wide grid.
// Numerics per matrix bit-identical to R23: value-bucket compaction (NB=60,
// W>=1.0, cat in En mantissa LSBs), exact weighted quartic rational (1 rcp /
// 4 a-terms, synthetic-division numerators, fp16-packed) + 3-term geometric
// tails, evaluated at 60 bucket-center nodes, 4-point Lagrange interpolation.
constexpr int B = 1024;
constexpr int NT = 256;
constexpr int NB = 60;
constexpr int SLOTCAP = 1216;
constexpr int QCAP = SLOTCAP / 4;  // 304
constexpr int QPHYS = QCAP + (QCAP >> 4) + 1;  // 324
constexpr float L2E = 1.4426950408889634f;
constexpr int TCOLS = NB + 6;      // 66

constexpr int OFF_EN  = 0;                        // 4864 B
constexpr int OFF_CQ  = OFF_EN + SLOTCAP * 4;     // CeAll+ChAll = 10368 B
                                                  //  (post-4: ANnode/APnode)
constexpr int OFF_SEG = OFF_CQ + 2 * QPHYS * 16;  // segCnt 960 + segPre 1920
                                                  //  (phase>=3: Tab 14x66x4)
constexpr int OFF_SST = OFF_SEG + 14 * TCOLS * 4; // segStart 61*4 = 244 B
constexpr int OFF_RED = OFF_SST + (NB + 1) * 4;   // Red 32 B
constexpr int POOL_BYTES = ((OFF_RED + 32 + 15) / 16) * 16;  // ~19.4 KB

__global__ __launch_bounds__(NT, 8)
void rank_one_kernel(const float* __restrict__ s_v, const float* __restrict__ s_l,
                     const int* __restrict__ pos_m, const int* __restrict__ neg_m,
                     const float* __restrict__ w_v, const float* __restrict__ w_l,
                     float* __restrict__ out) {
    __shared__ __align__(16) char pool[POOL_BYTES];
    float* En          = (float*)(pool + OFF_EN);
    float4* CeAll      = (float4*)(pool + OFF_CQ);
    uint4* ChAll       = (uint4*)(pool + OFF_CQ + QPHYS*16);
    unsigned char (*segCnt)[16]  = (unsigned char(*)[16])(pool + OFF_SEG);
    unsigned short (*segPre)[16] = (unsigned short(*)[16])(pool + OFF_SEG + NB*16);
    float* TabF        = (float*)(pool + OFF_SEG);
    int* segStart      = (int*)(pool + OFF_SST);
    float* Red         = (float*)(pool + OFF_RED);
    float* ANnode      = (float*)(pool + OFF_CQ);    // post-phase-4 overlay
    float* APnode      = ANnode + 64;

    const int m = blockIdx.x >> 10;
    const int r = blockIdx.x & 1023;
    const float* __restrict__ S = m ? s_l : s_v;
    const float* __restrict__ Wm = m ? w_l : w_v;
    const int tid = threadIdx.x;
    const int lane = tid & 63;
    const int wvid = tid >> 6;
    const unsigned long long lmask = (1ull << lane) - 1ull;

    for (int s = tid; s < SLOTCAP; s += NT) En[s] = 0.f;  // pads: cat bits 0
    for (int j = tid; j < NB * 16 / 4; j += NT) ((int*)segCnt)[j] = 0;
    __syncthreads();

    // ---- Phase 1: read, u = s/tau, cat, row min/max ----
    float uu[4]; int cat[4];
    float mn = 1e30f, mx = -1e30f;
#pragma unroll
    for (int i = 0; i < 4; ++i) {
        const int c = tid + i * NT;
        uu[i] = S[r * B + c] * 10.0f;
        const int pf = pos_m[r * B + c] != 0, nf = neg_m[r * B + c] != 0;
        cat[i] = pf | (nf << 1);
        mn = fminf(mn, uu[i]); mx = fmaxf(mx, uu[i]);
    }
#pragma unroll
    for (int off = 1; off < 64; off <<= 1) {
        mn = fminf(mn, __shfl_xor(mn, off));
        mx = fmaxf(mx, __shfl_xor(mx, off));
    }
    if (lane == 0) { Red[wvid] = mn; Red[4 + wvid] = mx; }
    __syncthreads();

    const float lo = fminf(fminf(Red[0], Red[1]), fminf(Red[2], Red[3]));
    const float hi = fmaxf(fmaxf(Red[4], Red[5]), fmaxf(Red[6], Red[7]));
    const float umin = lo;
    const float Wb   = fmaxf((hi - lo) * (1.0001f / NB), 1.0f);
    const float invW = 1.0f / Wb;
    const float kap1 = exp2f(-Wb * L2E);
    const float kap2 = kap1 * kap1;
    const float kap3 = kap2 * kap1;
    const float eWm  = exp2f(Wb * L2E);

    // ---- Phase 1b: bucket keys; rank via 6 bit-ballots (NB<63, cat0 -> 63) ----
    int key[4], rk[4];
#pragma unroll
    for (int i = 0; i < 4; ++i) {
        int b = (int)((uu[i] - umin) * invW);
        b = b > NB - 1 ? NB - 1 : b;
        const int kk = cat[i] ? b : 63;
        key[i] = b;
        unsigned long long same = ~0ull;
#pragma unroll
        for (int j = 0; j < 6; ++j) {
            const unsigned long long bb = __ballot((kk >> j) & 1);
            same &= ((kk >> j) & 1) ? bb : ~bb;
        }
        rk[i] = (int)__popcll(same & lmask);
        if (cat[i] && rk[i] == 0)
            segCnt[kk][i * 4 + wvid] = (unsigned char)__popcll(same);
    }
    __syncthreads();

    // ---- Phase 2a: segPre (parallel) + wave-0 shfl prefix scan of lengths ----
    for (int j = tid; j < NB * 16; j += NT) {
        const int k = j >> 4, u = j & 15;
        int p = 0;
        for (int v = 0; v < u; ++v) p += (int)segCnt[k][v];
        segPre[k][u] = (unsigned short)p;
    }
    if (wvid == 0) {
        int t = 0;
        if (lane < NB) {
#pragma unroll
            for (int u = 0; u < 16; ++u) t += (int)segCnt[lane][u];
            t = (t + 3) & ~3;
        }
        int inc = t;
#pragma unroll
        for (int d = 1; d < 64; d <<= 1) {
            const int o = __shfl_up(inc, d);
            if (lane >= d) inc += o;
        }
        if (lane < NB) segStart[lane] = inc - t;
        if (lane == NB - 1) segStart[NB] = inc;
    }
    __syncthreads();

    // ---- Phase 2b: placement (scatter En); cat in En mantissa LSBs ----
#pragma unroll
    for (int i = 0; i < 4; ++i) {
        if (cat[i]) {
            const int k = key[i];
            const int slot = segStart[k] + (int)segPre[k][i * 4 + wvid] + rk[i];
            const float cb = umin + ((float)k + 0.5f) * Wb;
            const float env = exp2f((uu[i] - cb) * L2E);
            unsigned eb = __float_as_uint(env);
            eb = (eb & ~3u) | (unsigned)cat[i];
            En[slot] = __uint_as_float(eb);
        }
    }
    __syncthreads();     // segCnt/segPre dead -> Tab overlay valid

    const int nS = segStart[NB];
    const int nQ = nS >> 2;

    // ---- Phase 3a: Tab boundary zeros + quad coefficients ----
    if (tid < 14 * 6) {                   // cols {0,1,62,63,64,65} per row
        const int row = tid / 6, ci = tid % 6;
        TabF[row * TCOLS + (ci < 2 ? ci : ci + 60)] = 0.f;  // disjoint from 3b's 2..61
    }
    for (int q = tid; q < nQ; q += NT) {
        const float4 e4v = *(const float4*)&En[4 * q];
        const float en[4] = {e4v.x, e4v.y, e4v.z, e4v.w};
        const int fl[4] = {(int)(__float_as_uint(e4v.x) & 3u),
                           (int)(__float_as_uint(e4v.y) & 3u),
                           (int)(__float_as_uint(e4v.z) & 3u),
                           (int)(__float_as_uint(e4v.w) & 3u)};
        const float s01 = en[0] + en[1], p01 = en[0] * en[1];
        const float s23 = en[2] + en[3], p23 = en[2] * en[3];
        const float e1 = s01 + s23;
        const float e2 = fmaf(s01, s23, p01 + p23);
        const float e3 = fmaf(s01, p23, s23 * p01);
        const float e4 = p01 * p23;
        float nA3 = 0.f, nA2 = 0.f, nA1 = 0.f, nA0 = 0.f;
        float nP3 = 0.f, nP2 = 0.f, nP1 = 0.f, nP0 = 0.f;
#pragma unroll
        for (int j = 0; j < 4; ++j) {
            const float b1 = e1 - en[j];
            const float b2 = fmaf(-en[j], b1, e2);
            const float b3 = fmaf(-en[j], b2, e3);
            const float nn = (float)(fl[j] >> 1) * en[j];
            const float pp = (float)(fl[j] & 1) * en[j];
            nA3 += nn; nA2 = fmaf(nn, b1, nA2); nA1 = fmaf(nn, b2, nA1); nA0 = fmaf(nn, b3, nA0);
            nP3 += pp; nP2 = fmaf(pp, b1, nP2); nP1 = fmaf(pp, b2, nP1); nP0 = fmaf(pp, b3, nP0);
        }
        const int pq = q + (q >> 4);   // bank-skewed physical index
        CeAll[pq] = make_float4(e1, e2, e3, e4);
        __half2 hA0 = __floats2half2_rn(nA3, nA2);
        __half2 hA1 = __floats2half2_rn(nA1, nA0);
        __half2 hP0 = __floats2half2_rn(nP3, nP2);
        __half2 hP1 = __floats2half2_rn(nP1, nP0);
        ChAll[pq] = make_uint4(reinterpret_cast<unsigned&>(hA0), reinterpret_cast<unsigned&>(hA1),
                               reinterpret_cast<unsigned&>(hP0), reinterpret_cast<unsigned&>(hP1));
    }
    // ---- Phase 3b: per-bucket tail sums, 4 threads/bucket + shfl reduce ----
    if (tid < NB * 4) {
        const int k = tid >> 2, o = tid & 3;
        float g1a=0,g2a=0,g3a=0,h1a=0,h2a=0,h3a=0,s0a=0;
        float g1p=0,g2p=0,g3p=0,h1p=0,h2p=0,h3p=0,s0p=0;
        for (int s = segStart[k] + o; s < segStart[k + 1]; s += 4) {
            const float en = En[s];
            const int f = (int)(__float_as_uint(en) & 3u);
            if (!f) continue;
            const float en2 = en * en, en3 = en2 * en;
            const float ren = __builtin_amdgcn_rcpf(en);
            const float ren2 = ren * ren, ren3 = ren2 * ren;
            const float nf = (float)(f >> 1), pf = (float)(f & 1);
            g1a = fmaf(nf,en,g1a);  g2a = fmaf(nf,en2,g2a);  g3a = fmaf(nf,en3,g3a);
            h1a = fmaf(nf,ren,h1a); h2a = fmaf(nf,ren2,h2a); h3a = fmaf(nf,ren3,h3a); s0a += nf;
            g1p = fmaf(pf,en,g1p);  g2p = fmaf(pf,en2,g2p);  g3p = fmaf(pf,en3,g3p);
            h1p = fmaf(pf,ren,h1p); h2p = fmaf(pf,ren2,h2p); h3p = fmaf(pf,ren3,h3p); s0p += pf;
        }
#define RED4(v) v += __shfl_xor(v, 2); v += __shfl_xor(v, 1)
        RED4(g1a); RED4(g2a); RED4(g3a); RED4(h1a); RED4(h2a); RED4(h3a); RED4(s0a);
        RED4(g1p); RED4(g2p); RED4(g3p); RED4(h1p); RED4(h2p); RED4(h3p); RED4(s0p);
#undef RED4
        if (o == 0) {
            TabF[(0*7+0)*TCOLS+k+2]=g1a; TabF[(0*7+1)*TCOLS+k+2]=g2a; TabF[(0*7+2)*TCOLS+k+2]=g3a;
            TabF[(0*7+3)*TCOLS+k+2]=h1a; TabF[(0*7+4)*TCOLS+k+2]=h2a; TabF[(0*7+5)*TCOLS+k+2]=h3a;
            TabF[(0*7+6)*TCOLS+k+2]=s0a;
            TabF[(1*7+0)*TCOLS+k+2]=g1p; TabF[(1*7+1)*TCOLS+k+2]=g2p; TabF[(1*7+2)*TCOLS+k+2]=g3p;
            TabF[(1*7+3)*TCOLS+k+2]=h1p; TabF[(1*7+4)*TCOLS+k+2]=h2p; TabF[(1*7+5)*TCOLS+k+2]=h3p;
            TabF[(1*7+6)*TCOLS+k+2]=s0p;
        }
    }
    __syncthreads();
    // ---- Phase 3c: wave-parallel weighted scans (14 rows over 4 waves) ----
    for (int rowi = wvid; rowi < 14; rowi += 4) {
        const int r7 = rowi % 7;
        float* Trow = &TabF[rowi * TCOLS];
        float v = (lane < NB) ? Trow[lane + 2] : 0.f;
        if (r7 < 3) {          // prefix: y[k] = x[k] + kp*y[k-1]
            float kp = (r7 == 0) ? kap1 : (r7 == 1 ? kap2 : kap3);
#pragma unroll
            for (int d = 1; d < 64; d <<= 1) {
                const float o = __shfl_up(v, d);
                if (lane >= d) v = fmaf(kp, o, v);
                kp *= kp;
            }
        } else {               // suffix: y[k] = x[k] + kp*y[k+1]  (kp=1: plain sum)
            float kp = (r7 == 3) ? kap1 : (r7 == 4 ? kap2 : (r7 == 5 ? kap3 : 1.0f));
#pragma unroll
            for (int d = 1; d < 64; d <<= 1) {
                float o = __shfl_down(v, d);
                if (lane + d > 63) o = 0.f;
                v = fmaf(kp, o, v);
                kp *= kp;
            }
        }
        if (lane < NB) Trow[lane + 2] = v;
    }
    __syncthreads();

    // ---- Phase 4: node evaluation (4 threads per node) ----
    const int nd = tid >> 2;           // node = bucket center index
    const int no = tid & 3;
    float ANv = 0.f, APv = 0.f;
    if (nd < NB) {
        const int klo = nd > 0 ? nd - 1 : 0;
        const int khi = nd < NB - 1 ? nd + 1 : NB - 1;
        const int qs  = segStart[klo] >> 2;
        const int qe  = segStart[khi + 1] >> 2;
        const int qo0 = segStart[nd] >> 2;
        const int qo1 = segStart[nd + 1] >> 2;
        for (int q = qs + no; q < qe; q += 4) {
            const float x = (q < qo0) ? eWm : ((q >= qo1) ? kap1 : 1.0f);
            const int pq = q + (q >> 4);
            const float4 ce = CeAll[pq];
            const uint4 ch = ChAll[pq];
            const float2 a01 = __half22float2(*(const __half2*)&ch.x);
            const float2 a23 = __half22float2(*(const __half2*)&ch.y);
            const float2 p01 = __half22float2(*(const __half2*)&ch.z);
            const float2 p23 = __half22float2(*(const __half2*)&ch.w);
            float t = x + ce.x; t = fmaf(t, x, ce.y); t = fmaf(t, x, ce.z);
            const float D = fmaf(t, x, ce.w);
            float u = fmaf(a01.x, x, a01.y); u = fmaf(u, x, a23.x);
            const float NA = fmaf(u, x, a23.y);
            float v = fmaf(p01.x, x, p01.y); v = fmaf(v, x, p23.x);
            const float NP = fmaf(v, x, p23.y);
            const float rd = __builtin_amdgcn_rcpf(D);
            ANv = fmaf(NA, rd, ANv);
            APv = fmaf(NP, rd, APv);
        }
        ANv += __shfl_xor(ANv, 2); ANv += __shfl_xor(ANv, 1);
        APv += __shfl_xor(APv, 2); APv += __shfl_xor(APv, 1);
        // tails at node (eb = 1 -> all factors are kappa2 powers)
        const float k2 = kap2, k4 = kap2 * kap2, k6 = k4 * kap2;
        ANv += k2 * TabF[(0*7+0)*TCOLS+nd] - k4 * TabF[(0*7+1)*TCOLS+nd] + k6 * TabF[(0*7+2)*TCOLS+nd]
             + TabF[(0*7+6)*TCOLS+nd+4] - k2 * TabF[(0*7+3)*TCOLS+nd+4]
             + k4 * TabF[(0*7+4)*TCOLS+nd+4] - k6 * TabF[(0*7+5)*TCOLS+nd+4];
        APv += k2 * TabF[(1*7+0)*TCOLS+nd] - k4 * TabF[(1*7+1)*TCOLS+nd] + k6 * TabF[(1*7+2)*TCOLS+nd]
             + TabF[(1*7+6)*TCOLS+nd+4] - k2 * TabF[(1*7+3)*TCOLS+nd+4]
             + k4 * TabF[(1*7+4)*TCOLS+nd+4] - k6 * TabF[(1*7+5)*TCOLS+nd+4];
    }
    __syncthreads();   // Cq reads done -> node arrays may overlay
    if (nd < NB && no == 0) { ANnode[nd] = ANv; APnode[nd] = APv; }
    __syncthreads();

    // ---- Phase 5: per-item cubic interpolation + atomic output term ----
#pragma unroll
    for (int i = 0; i < 4; ++i) {
        const int c = tid + i * NT;
        const float t = (uu[i] - umin) * invW - 0.5f;   // node j sits at t = j
        int jc = (int)floorf(t);
        jc = jc < 1 ? 1 : (jc > NB - 3 ? NB - 3 : jc);
        const float s = t - (float)jc;
        const float sm = s - 1.f, sp = s + 1.f, s2 = s - 2.f;
        const float wL = -s * sm * s2 * (1.f / 6.f);
        const float w0 = sp * sm * s2 * 0.5f;
        const float w1 = -sp * s * s2 * 0.5f;
        const float w2 = sp * s * sm * (1.f / 6.f);
        const float AN = wL * ANnode[jc-1] + w0 * ANnode[jc] + w1 * ANnode[jc+1] + w2 * ANnode[jc+2];
        const float AP = wL * APnode[jc-1] + w0 * APnode[jc] + w1 * APnode[jc+1] + w2 * APnode[jc+2];
        const bool pf = (cat[i] & 1) != 0;
        const bool nf = (cat[i] & 2) != 0;
        const float rk_ = (pf ? 1.f + AN : 0.f) + (nf ? 1.f + AP : 0.f);
        const float term = 61.f * Wm[r * B + c] / (60.f + rk_);
        atomicAdd(&out[r * B + c], term);   // exactly 2 commutative adds/elem
    }
}

extern "C" void kernel_launch(void* const* d_in, const int* in_sizes, int n_in,
                              void* d_out, int out_size, void* d_ws, size_t ws_size,
                              hipStream_t stream) {
    const float* s_v = (const float*)d_in[0];
    const float* s_l = (const float*)d_in[1];
    const int* pos_mask = (const int*)d_in[2];
    const int* neg_mask = (const int*)d_in[3];
    const float* w_v = (const float*)d_in[4];
    const float* w_l = (const float*)d_in[5];
    float* out = (float*)d_out;

    hipMemsetAsync(out, 0, (size_t)out_size * sizeof(float), stream);
    rank_one_kernel<<<2 * B, NT, 0, stream>>>(s_v, s_l, pos_mask, neg_mask,
                                              w_v, w_l, out);
}

// Round 26
// 30.999 us; speedup vs baseline: 1.3223x; 1.0717x over previous
//
#include <hip/hip_runtime.h>
#include <hip/hip_fp16.h>

// DifferentiableRankIntegration, B=1024, tau=0.1, K=60.
// R26 = R23 (best structure: 2048 blocks, one per (matrix,row), write-only
// stores, separate combine) with the division moved INTO the rank kernel:
// ws holds the output TERM 61*w_m/(60+rank_m), so combine is a pure
// 2-load/1-store add (8MB less traffic). R24/R25 lessons: fusion halves
// grid parallelism; atomics add RMW + cross-XCD line contention — both lose.
// Numerics per matrix bit-identical to R23: value-bucket compaction (NB=60,
// W>=1.0, cat in En mantissa LSBs), exact weighted quartic rational (1 rcp /
// 4 a-terms, synthetic-division numerators, fp16-packed) + 3-term geometric
// tails, evaluated at 60 bucket-center nodes, 4-point Lagrange interpolation.
constexpr int B = 1024;
constexpr int NT = 256;
constexpr int NB = 60;
constexpr int SLOTCAP = 1216;
constexpr int QCAP = SLOTCAP / 4;  // 304
constexpr int QPHYS = QCAP + (QCAP >> 4) + 1;  // 324
constexpr float L2E = 1.4426950408889634f;
constexpr int TCOLS = NB + 6;      // 66

constexpr int OFF_EN  = 0;                        // 4864 B
constexpr int OFF_CQ  = OFF_EN + SLOTCAP * 4;     // CeAll+ChAll = 10368 B
                                                  //  (post-4: ANnode/APnode)
constexpr int OFF_SEG = OFF_CQ + 2 * QPHYS * 16;  // segCnt 960 + segPre 1920
                                                  //  (phase>=3: Tab 14x66x4)
constexpr int OFF_SST = OFF_SEG + 14 * TCOLS * 4; // segStart 61*4 = 244 B
constexpr int OFF_RED = OFF_SST + (NB + 1) * 4;   // Red 32 B
constexpr int POOL_BYTES = ((OFF_RED + 32 + 15) / 16) * 16;  // ~19.4 KB

__global__ __launch_bounds__(NT, 8)
void rank_one_kernel(const float* __restrict__ s_v, const float* __restrict__ s_l,
                     const int* __restrict__ pos_m, const int* __restrict__ neg_m,
                     const float* __restrict__ w_v, const float* __restrict__ w_l,
                     float* __restrict__ term_ws) {
    __shared__ __align__(16) char pool[POOL_BYTES];
    float* En          = (float*)(pool + OFF_EN);
    float4* CeAll      = (float4*)(pool + OFF_CQ);
    uint4* ChAll       = (uint4*)(pool + OFF_CQ + QPHYS*16);
    unsigned char (*segCnt)[16]  = (unsigned char(*)[16])(pool + OFF_SEG);
    unsigned short (*segPre)[16] = (unsigned short(*)[16])(pool + OFF_SEG + NB*16);
    float* TabF        = (float*)(pool + OFF_SEG);
    int* segStart      = (int*)(pool + OFF_SST);
    float* Red         = (float*)(pool + OFF_RED);
    float* ANnode      = (float*)(pool + OFF_CQ);    // post-phase-4 overlay
    float* APnode      = ANnode + 64;

    const int m = blockIdx.x >> 10;
    const int r = blockIdx.x & 1023;
    const float* __restrict__ S = m ? s_l : s_v;
    const float* __restrict__ Wm = m ? w_l : w_v;
    const int tid = threadIdx.x;
    const int lane = tid & 63;
    const int wvid = tid >> 6;
    const unsigned long long lmask = (1ull << lane) - 1ull;

    for (int s = tid; s < SLOTCAP; s += NT) En[s] = 0.f;  // pads: cat bits 0
    for (int j = tid; j < NB * 16 / 4; j += NT) ((int*)segCnt)[j] = 0;
    __syncthreads();

    // ---- Phase 1: read, u = s/tau, cat, row min/max ----
    float uu[4]; int cat[4];
    float mn = 1e30f, mx = -1e30f;
#pragma unroll
    for (int i = 0; i < 4; ++i) {
        const int c = tid + i * NT;
        uu[i] = S[r * B + c] * 10.0f;
        const int pf = pos_m[r * B + c] != 0, nf = neg_m[r * B + c] != 0;
        cat[i] = pf | (nf << 1);
        mn = fminf(mn, uu[i]); mx = fmaxf(mx, uu[i]);
    }
#pragma unroll
    for (int off = 1; off < 64; off <<= 1) {
        mn = fminf(mn, __shfl_xor(mn, off));
        mx = fmaxf(mx, __shfl_xor(mx, off));
    }
    if (lane == 0) { Red[wvid] = mn; Red[4 + wvid] = mx; }
    __syncthreads();

    const float lo = fminf(fminf(Red[0], Red[1]), fminf(Red[2], Red[3]));
    const float hi = fmaxf(fmaxf(Red[4], Red[5]), fmaxf(Red[6], Red[7]));
    const float umin = lo;
    const float Wb   = fmaxf((hi - lo) * (1.0001f / NB), 1.0f);
    const float invW = 1.0f / Wb;
    const float kap1 = exp2f(-Wb * L2E);
    const float kap2 = kap1 * kap1;
    const float kap3 = kap2 * kap1;
    const float eWm  = exp2f(Wb * L2E);

    // ---- Phase 1b: bucket keys; rank via 6 bit-ballots (NB<63, cat0 -> 63) ----
    int key[4], rk[4];
#pragma unroll
    for (int i = 0; i < 4; ++i) {
        int b = (int)((uu[i] - umin) * invW);
        b = b > NB - 1 ? NB - 1 : b;
        const int kk = cat[i] ? b : 63;
        key[i] = b;
        unsigned long long same = ~0ull;
#pragma unroll
        for (int j = 0; j < 6; ++j) {
            const unsigned long long bb = __ballot((kk >> j) & 1);
            same &= ((kk >> j) & 1) ? bb : ~bb;
        }
        rk[i] = (int)__popcll(same & lmask);
        if (cat[i] && rk[i] == 0)
            segCnt[kk][i * 4 + wvid] = (unsigned char)__popcll(same);
    }
    __syncthreads();

    // ---- Phase 2a: segPre (parallel) + wave-0 shfl prefix scan of lengths ----
    for (int j = tid; j < NB * 16; j += NT) {
        const int k = j >> 4, u = j & 15;
        int p = 0;
        for (int v = 0; v < u; ++v) p += (int)segCnt[k][v];
        segPre[k][u] = (unsigned short)p;
    }
    if (wvid == 0) {
        int t = 0;
        if (lane < NB) {
#pragma unroll
            for (int u = 0; u < 16; ++u) t += (int)segCnt[lane][u];
            t = (t + 3) & ~3;
        }
        int inc = t;
#pragma unroll
        for (int d = 1; d < 64; d <<= 1) {
            const int o = __shfl_up(inc, d);
            if (lane >= d) inc += o;
        }
        if (lane < NB) segStart[lane] = inc - t;
        if (lane == NB - 1) segStart[NB] = inc;
    }
    __syncthreads();

    // ---- Phase 2b: placement (scatter En); cat in En mantissa LSBs ----
#pragma unroll
    for (int i = 0; i < 4; ++i) {
        if (cat[i]) {
            const int k = key[i];
            const int slot = segStart[k] + (int)segPre[k][i * 4 + wvid] + rk[i];
            const float cb = umin + ((float)k + 0.5f) * Wb;
            const float env = exp2f((uu[i] - cb) * L2E);
            unsigned eb = __float_as_uint(env);
            eb = (eb & ~3u) | (unsigned)cat[i];
            En[slot] = __uint_as_float(eb);
        }
    }
    __syncthreads();     // segCnt/segPre dead -> Tab overlay valid

    const int nS = segStart[NB];
    const int nQ = nS >> 2;

    // ---- Phase 3a: Tab boundary zeros + quad coefficients ----
    if (tid < 14 * 6) {                   // cols {0,1,62,63,64,65} per row
        const int row = tid / 6, ci = tid % 6;
        TabF[row * TCOLS + (ci < 2 ? ci : ci + 60)] = 0.f;  // disjoint from 3b's 2..61
    }
    for (int q = tid; q < nQ; q += NT) {
        const float4 e4v = *(const float4*)&En[4 * q];
        const float en[4] = {e4v.x, e4v.y, e4v.z, e4v.w};
        const int fl[4] = {(int)(__float_as_uint(e4v.x) & 3u),
                           (int)(__float_as_uint(e4v.y) & 3u),
                           (int)(__float_as_uint(e4v.z) & 3u),
                           (int)(__float_as_uint(e4v.w) & 3u)};
        const float s01 = en[0] + en[1], p01 = en[0] * en[1];
        const float s23 = en[2] + en[3], p23 = en[2] * en[3];
        const float e1 = s01 + s23;
        const float e2 = fmaf(s01, s23, p01 + p23);
        const float e3 = fmaf(s01, p23, s23 * p01);
        const float e4 = p01 * p23;
        float nA3 = 0.f, nA2 = 0.f, nA1 = 0.f, nA0 = 0.f;
        float nP3 = 0.f, nP2 = 0.f, nP1 = 0.f, nP0 = 0.f;
#pragma unroll
        for (int j = 0; j < 4; ++j) {
            const float b1 = e1 - en[j];
            const float b2 = fmaf(-en[j], b1, e2);
            const float b3 = fmaf(-en[j], b2, e3);
            const float nn = (float)(fl[j] >> 1) * en[j];
            const float pp = (float)(fl[j] & 1) * en[j];
            nA3 += nn; nA2 = fmaf(nn, b1, nA2); nA1 = fmaf(nn, b2, nA1); nA0 = fmaf(nn, b3, nA0);
            nP3 += pp; nP2 = fmaf(pp, b1, nP2); nP1 = fmaf(pp, b2, nP1); nP0 = fmaf(pp, b3, nP0);
        }
        const int pq = q + (q >> 4);   // bank-skewed physical index
        CeAll[pq] = make_float4(e1, e2, e3, e4);
        __half2 hA0 = __floats2half2_rn(nA3, nA2);
        __half2 hA1 = __floats2half2_rn(nA1, nA0);
        __half2 hP0 = __floats2half2_rn(nP3, nP2);
        __half2 hP1 = __floats2half2_rn(nP1, nP0);
        ChAll[pq] = make_uint4(reinterpret_cast<unsigned&>(hA0), reinterpret_cast<unsigned&>(hA1),
                               reinterpret_cast<unsigned&>(hP0), reinterpret_cast<unsigned&>(hP1));
    }
    // ---- Phase 3b: per-bucket tail sums, 4 threads/bucket + shfl reduce ----
    if (tid < NB * 4) {
        const int k = tid >> 2, o = tid & 3;
        float g1a=0,g2a=0,g3a=0,h1a=0,h2a=0,h3a=0,s0a=0;
        float g1p=0,g2p=0,g3p=0,h1p=0,h2p=0,h3p=0,s0p=0;
        for (int s = segStart[k] + o; s < segStart[k + 1]; s += 4) {
            const float en = En[s];
            const int f = (int)(__float_as_uint(en) & 3u);
            if (!f) continue;
            const float en2 = en * en, en3 = en2 * en;
            const float ren = __builtin_amdgcn_rcpf(en);
            const float ren2 = ren * ren, ren3 = ren2 * ren;
            const float nf = (float)(f >> 1), pf = (float)(f & 1);
            g1a = fmaf(nf,en,g1a);  g2a = fmaf(nf,en2,g2a);  g3a = fmaf(nf,en3,g3a);
            h1a = fmaf(nf,ren,h1a); h2a = fmaf(nf,ren2,h2a); h3a = fmaf(nf,ren3,h3a); s0a += nf;
            g1p = fmaf(pf,en,g1p);  g2p = fmaf(pf,en2,g2p);  g3p = fmaf(pf,en3,g3p);
            h1p = fmaf(pf,ren,h1p); h2p = fmaf(pf,ren2,h2p); h3p = fmaf(pf,ren3,h3p); s0p += pf;
        }
#define RED4(v) v += __shfl_xor(v, 2); v += __shfl_xor(v, 1)
        RED4(g1a); RED4(g2a); RED4(g3a); RED4(h1a); RED4(h2a); RED4(h3a); RED4(s0a);
        RED4(g1p); RED4(g2p); RED4(g3p); RED4(h1p); RED4(h2p); RED4(h3p); RED4(s0p);
#undef RED4
        if (o == 0) {
            TabF[(0*7+0)*TCOLS+k+2]=g1a; TabF[(0*7+1)*TCOLS+k+2]=g2a; TabF[(0*7+2)*TCOLS+k+2]=g3a;
            TabF[(0*7+3)*TCOLS+k+2]=h1a; TabF[(0*7+4)*TCOLS+k+2]=h2a; TabF[(0*7+5)*TCOLS+k+2]=h3a;
            TabF[(0*7+6)*TCOLS+k+2]=s0a;
            TabF[(1*7+0)*TCOLS+k+2]=g1p; TabF[(1*7+1)*TCOLS+k+2]=g2p; TabF[(1*7+2)*TCOLS+k+2]=g3p;
            TabF[(1*7+3)*TCOLS+k+2]=h1p; TabF[(1*7+4)*TCOLS+k+2]=h2p; TabF[(1*7+5)*TCOLS+k+2]=h3p;
            TabF[(1*7+6)*TCOLS+k+2]=s0p;
        }
    }
    __syncthreads();
    // ---- Phase 3c: wave-parallel weighted scans (14 rows over 4 waves) ----
    for (int rowi = wvid; rowi < 14; rowi += 4) {
        const int r7 = rowi % 7;
        float* Trow = &TabF[rowi * TCOLS];
        float v = (lane < NB) ? Trow[lane + 2] : 0.f;
        if (r7 < 3) {          // prefix: y[k] = x[k] + kp*y[k-1]
            float kp = (r7 == 0) ? kap1 : (r7 == 1 ? kap2 : kap3);
#pragma unroll
            for (int d = 1; d < 64; d <<= 1) {
                const float o = __shfl_up(v, d);
                if (lane >= d) v = fmaf(kp, o, v);
                kp *= kp;
            }
        } else {               // suffix: y[k] = x[k] + kp*y[k+1]  (kp=1: plain sum)
            float kp = (r7 == 3) ? kap1 : (r7 == 4 ? kap2 : (r7 == 5 ? kap3 : 1.0f));
#pragma unroll
            for (int d = 1; d < 64; d <<= 1) {
                float o = __shfl_down(v, d);
                if (lane + d > 63) o = 0.f;
                v = fmaf(kp, o, v);
                kp *= kp;
            }
        }
        if (lane < NB) Trow[lane + 2] = v;
    }
    __syncthreads();

    // ---- Phase 4: node evaluation (4 threads per node) ----
    const int nd = tid >> 2;           // node = bucket center index
    const int no = tid & 3;
    float ANv = 0.f, APv = 0.f;
    if (nd < NB) {
        const int klo = nd > 0 ? nd - 1 : 0;
        const int khi = nd < NB - 1 ? nd + 1 : NB - 1;
        const int qs  = segStart[klo] >> 2;
        const int qe  = segStart[khi + 1] >> 2;
        const int qo0 = segStart[nd] >> 2;
        const int qo1 = segStart[nd + 1] >> 2;
        for (int q = qs + no; q < qe; q += 4) {
            const float x = (q < qo0) ? eWm : ((q >= qo1) ? kap1 : 1.0f);
            const int pq = q + (q >> 4);
            const float4 ce = CeAll[pq];
            const uint4 ch = ChAll[pq];
            const float2 a01 = __half22float2(*(const __half2*)&ch.x);
            const float2 a23 = __half22float2(*(const __half2*)&ch.y);
            const float2 p01 = __half22float2(*(const __half2*)&ch.z);
            const float2 p23 = __half22float2(*(const __half2*)&ch.w);
            float t = x + ce.x; t = fmaf(t, x, ce.y); t = fmaf(t, x, ce.z);
            const float D = fmaf(t, x, ce.w);
            float u = fmaf(a01.x, x, a01.y); u = fmaf(u, x, a23.x);
            const float NA = fmaf(u, x, a23.y);
            float v = fmaf(p01.x, x, p01.y); v = fmaf(v, x, p23.x);
            const float NP = fmaf(v, x, p23.y);
            const float rd = __builtin_amdgcn_rcpf(D);
            ANv = fmaf(NA, rd, ANv);
            APv = fmaf(NP, rd, APv);
        }
        ANv += __shfl_xor(ANv, 2); ANv += __shfl_xor(ANv, 1);
        APv += __shfl_xor(APv, 2); APv += __shfl_xor(APv, 1);
        // tails at node (eb = 1 -> all factors are kappa2 powers)
        const float k2 = kap2, k4 = kap2 * kap2, k6 = k4 * kap2;
        ANv += k2 * TabF[(0*7+0)*TCOLS+nd] - k4 * TabF[(0*7+1)*TCOLS+nd] + k6 * TabF[(0*7+2)*TCOLS+nd]
             + TabF[(0*7+6)*TCOLS+nd+4] - k2 * TabF[(0*7+3)*TCOLS+nd+4]
             + k4 * TabF[(0*7+4)*TCOLS+nd+4] - k6 * TabF[(0*7+5)*TCOLS+nd+4];
        APv += k2 * TabF[(1*7+0)*TCOLS+nd] - k4 * TabF[(1*7+1)*TCOLS+nd] + k6 * TabF[(1*7+2)*TCOLS+nd]
             + TabF[(1*7+6)*TCOLS+nd+4] - k2 * TabF[(1*7+3)*TCOLS+nd+4]
             + k4 * TabF[(1*7+4)*TCOLS+nd+4] - k6 * TabF[(1*7+5)*TCOLS+nd+4];
    }
    __syncthreads();   // Cq reads done -> node arrays may overlay
    if (nd < NB && no == 0) { ANnode[nd] = ANv; APnode[nd] = APv; }
    __syncthreads();

    // ---- Phase 5: cubic interpolation + output TERM to ws ----
#pragma unroll
    for (int i = 0; i < 4; ++i) {
        const int c = tid + i * NT;
        const float t = (uu[i] - umin) * invW - 0.5f;   // node j sits at t = j
        int jc = (int)floorf(t);
        jc = jc < 1 ? 1 : (jc > NB - 3 ? NB - 3 : jc);
        const float s = t - (float)jc;
        const float sm = s - 1.f, sp = s + 1.f, s2 = s - 2.f;
        const float wL = -s * sm * s2 * (1.f / 6.f);
        const float w0 = sp * sm * s2 * 0.5f;
        const float w1 = -sp * s * s2 * 0.5f;
        const float w2 = sp * s * sm * (1.f / 6.f);
        const float AN = wL * ANnode[jc-1] + w0 * ANnode[jc] + w1 * ANnode[jc+1] + w2 * ANnode[jc+2];
        const float AP = wL * APnode[jc-1] + w0 * APnode[jc] + w1 * APnode[jc+1] + w2 * APnode[jc+2];
        const bool pf = (cat[i] & 1) != 0;
        const bool nf = (cat[i] & 2) != 0;
        const float rk_ = (pf ? 1.f + AN : 0.f) + (nf ? 1.f + AP : 0.f);
        term_ws[m * (B * B) + r * B + c] = 61.f * Wm[r * B + c] / (60.f + rk_);
    }
}

__global__ __launch_bounds__(NT, 8)
void combine_kernel(const float* __restrict__ term_ws, float* __restrict__ out) {
    const int i4 = (blockIdx.x * NT + threadIdx.x) * 4;
    const float4 tv = *(const float4*)&term_ws[i4];
    const float4 tl = *(const float4*)&term_ws[B * B + i4];
    float4 o;
    o.x = tv.x + tl.x;
    o.y = tv.y + tl.y;
    o.z = tv.z + tl.z;
    o.w = tv.w + tl.w;
    *(float4*)&out[i4] = o;
}

extern "C" void kernel_launch(void* const* d_in, const int* in_sizes, int n_in,
                              void* d_out, int out_size, void* d_ws, size_t ws_size,
                              hipStream_t stream) {
    const float* s_v = (const float*)d_in[0];
    const float* s_l = (const float*)d_in[1];
    const int* pos_mask = (const int*)d_in[2];
    const int* neg_mask = (const int*)d_in[3];
    const float* w_v = (const float*)d_in[4];
    const float* w_l = (const float*)d_in[5];
    float* out = (float*)d_out;
    float* term_ws = (float*)d_ws;   // 2 * 1024 * 1024 floats = 8 MB

    rank_one_kernel<<<2 * B, NT, 0, stream>>>(s_v, s_l, pos_mask, neg_mask,
                                              w_v, w_l, term_ws);
    combine_kernel<<<(B * B) / (NT * 4), NT, 0, stream>>>(term_ws, out);
}